// Round 9
// baseline (509.747 us; speedup 1.0000x reference)
//
#include <hip/hip_runtime.h>

#define DIMC 384
#define NHEADS 12
#define NTOK 144
#define TABLEN 529
#define BWIN 512
#define NWIN 16
#define CPBH 512

typedef unsigned short u16;
typedef unsigned int u32;
typedef __attribute__((ext_vector_type(8))) short short8;
typedef __attribute__((ext_vector_type(4))) float f32x4;

#define MFMA(a, b, c) __builtin_amdgcn_mfma_f32_16x16x32_bf16((a), (b), (c), 0, 0, 0)

__device__ __forceinline__ u16 f2bf(float f) {
  union { float f; u32 u; } v; v.f = f;
  u32 r = v.u + 0x7fffu + ((v.u >> 16) & 1u);
  return (u16)(r >> 16);
}
__device__ __forceinline__ u32 pk2(float a, float b) {
  return (u32)f2bf(a) | ((u32)f2bf(b) << 16);
}
__device__ __forceinline__ int swz4(int r) { return (r ^ (r >> 2)) & 3; }

// ---------------- f32 -> bf16 bulk convert ----------------
__global__ __launch_bounds__(256) void cvt_bf16(const float* __restrict__ in,
                                                u16* __restrict__ out, int n8) {
  int i = blockIdx.x * 256 + threadIdx.x;
  if (i >= n8) return;
  const float4* p = (const float4*)(in + (size_t)i * 8);
  float4 a = p[0], b = p[1];
  uint4 r;
  r.x = pk2(a.x, a.y); r.y = pk2(a.z, a.w);
  r.z = pk2(b.x, b.y); r.w = pk2(b.z, b.w);
  *(uint4*)(out + (size_t)i * 8) = r;
}

// ---------------- CPB-MLP table (529 x 12, sigmoid applied) + per-head scales ----------------
__global__ void cpb_kernel(const float* __restrict__ rct,
                           const float* __restrict__ w1,
                           const float* __restrict__ b1,
                           const float* __restrict__ w2,
                           const float* __restrict__ logit_scale,
                           float* __restrict__ bias_tab,
                           float* __restrict__ scalev) {
  int t = blockIdx.x * blockDim.x + threadIdx.x;
  if (t < NHEADS) scalev[t] = __expf(fminf(logit_scale[t], 4.60517018598809f));
  if (t >= TABLEN * NHEADS) return;
  int i = t / NHEADS, h = t % NHEADS;
  float c0 = rct[2 * i], c1 = rct[2 * i + 1];
  const float* w2h = w2 + (size_t)h * CPBH;
  float acc = 0.f;
  for (int k = 0; k < CPBH; ++k) {
    float hv = fmaxf(0.f, fmaf(c0, w1[2 * k], fmaf(c1, w1[2 * k + 1], b1[k])));
    acc = fmaf(hv, w2h[k], acc);
  }
  bias_tab[i * NHEADS + h] = 16.f / (1.f + __expf(-acc));
}

// ---------------- combined bias: cb[w][h][n][m] = rpb + mask (fp32) ----------------
__global__ __launch_bounds__(256) void cbias_kernel(const int* __restrict__ rpi,
                                                    const float* __restrict__ bias_tab,
                                                    const float* __restrict__ mask,
                                                    float* __restrict__ cb) {
  int e = blockIdx.x * 256 + threadIdx.x;
  if (e >= NWIN * NHEADS * NTOK * NTOK) return;
  int m = e % NTOK;
  int t = e / NTOK;
  int n = t % NTOK; t /= NTOK;
  int h = t % NHEADS;
  int w = t / NHEADS;
  cb[e] = bias_tab[rpi[n * NTOK + m] * NHEADS + h] + mask[(w * NTOK + n) * NTOK + m];
}

// ---------------- fused QKV-projection + cosine attention per (window b, head h) ----------------
// 192 threads = 3 waves; wave wv owns query rows [48wv, 48wv+48).
// Block decode is w-grouped per XCD: XCD x handles mask-windows {2x, 2x+1} so its
// cb working set (2 x 1.2MB) fits the 4MB XCD L2. Heads of one b are consecutive bids.
// Phase 1 = R2-proven register-prefetch schedule (K=32, loads issued one full iter
// ahead; 124 VGPR, zero spill) with R6-proven XOR-swizzled staging (conflict-free).
__global__ __launch_bounds__(192) void attn_fused(
    const u16* __restrict__ xb, const u16* __restrict__ wb,
    const float* __restrict__ q_bias, const float* __restrict__ k_bias,
    const float* __restrict__ v_bias, const float* __restrict__ cb,
    const float* __restrict__ scalev, u16* __restrict__ ctx) {
  __shared__ u16 smem[22656];  // 45312 B -> 3 blocks/CU
  u16* qn = smem;               // [144][40] (phase 2+)
  u16* kn = smem + 5760;        // [144][40] (phase 2+)
  u16* vT = smem + 11520;       // [32][168] (phase 2+)
  u16* Pc = smem + 16896;       // [144][40] (phase 5)
  u16* xs = smem;               // phase 1: [144][32] swizzled x chunk (9216 B)
  u16* wsm = smem + 4608;       // phase 1: [96][32] swizzled W chunk (6144 B)

  // w-grouped XCD decode
  int bid = blockIdx.x;
  int xcd = bid & 7;
  int i = bid >> 3;          // 0..767
  int wsub = i / 384;        // 0..1
  int j = i - wsub * 384;    // 0..383
  int bI = j / NHEADS;       // 0..31
  int h = j - bI * NHEADS;   // 0..11
  int w = xcd * 2 + wsub;    // 0..15
  int b = bI * NWIN + w;     // 0..511

  int tid = threadIdx.x;
  int lane = tid & 63, wv = tid >> 6;
  int g = lane >> 4, c = lane & 15;
  int rbase = wv * 48;

  // ---- phase 1: QKV projection via MFMA, K chunked by 32 (R2 schedule) ----
  f32x4 acc[3][6];
#pragma unroll
  for (int a = 0; a < 3; ++a)
#pragma unroll
    for (int d = 0; d < 6; ++d) acc[a][d] = (f32x4){0.f, 0.f, 0.f, 0.f};

  int r4 = tid >> 2, b4 = tid & 3;
  uint4 px[3], pw[2];
#pragma unroll
  for (int p = 0; p < 3; ++p)
    px[p] = *(const uint4*)(xb + ((size_t)b * NTOK + p * 48 + r4) * DIMC + b4 * 8);
#pragma unroll
  for (int p = 0; p < 2; ++p) {
    int row = p * 48 + r4;
    int wrow = (row >> 5) * DIMC + h * 32 + (row & 31);
    pw[p] = *(const uint4*)(wb + (size_t)wrow * DIMC + b4 * 8);
  }

  for (int t = 0; t < 12; ++t) {
    // swizzled staging writes (content block b4 -> slot b4 ^ swz4(row))
#pragma unroll
    for (int p = 0; p < 3; ++p) {
      int row = p * 48 + r4;
      *(uint4*)(xs + row * 32 + 8 * (b4 ^ swz4(row))) = px[p];
    }
#pragma unroll
    for (int p = 0; p < 2; ++p) {
      int row = p * 48 + r4;
      *(uint4*)(wsm + row * 32 + 8 * (b4 ^ swz4(row))) = pw[p];
    }
    __syncthreads();
    if (t < 11) {  // prefetch next tile into registers (one full iter of coverage)
      int k0 = (t + 1) * 32;
#pragma unroll
      for (int p = 0; p < 3; ++p)
        px[p] = *(const uint4*)(xb + ((size_t)b * NTOK + p * 48 + r4) * DIMC + k0 + b4 * 8);
#pragma unroll
      for (int p = 0; p < 2; ++p) {
        int row = p * 48 + r4;
        int wrow = (row >> 5) * DIMC + h * 32 + (row & 31);
        pw[p] = *(const uint4*)(wb + (size_t)wrow * DIMC + k0 + b4 * 8);
      }
    }
    short8 ax[3];
#pragma unroll
    for (int nt = 0; nt < 3; ++nt) {
      int row = rbase + nt * 16 + c;
      ax[nt] = *(const short8*)(xs + row * 32 + 8 * (g ^ swz4(row)));
    }
#pragma unroll
    for (int ni = 0; ni < 6; ++ni) {
      int row = ni * 16 + c;
      short8 bw = *(const short8*)(wsm + row * 32 + 8 * (g ^ swz4(row)));
#pragma unroll
      for (int nt = 0; nt < 3; ++nt) acc[nt][ni] = MFMA(ax[nt], bw, acc[nt][ni]);
    }
    __syncthreads();
  }

  // ---- phase 2: bias + cosine-normalize in-register, write qn/kn/vT (R2-proven) ----
  float sch = scalev[h];
  float qb0 = q_bias[h * 32 + c], qb1 = q_bias[h * 32 + 16 + c];
  float kb0 = k_bias[h * 32 + c], kb1 = k_bias[h * 32 + 16 + c];
  float vb0 = v_bias[h * 32 + c], vb1 = v_bias[h * 32 + 16 + c];
#pragma unroll
  for (int nt = 0; nt < 3; ++nt) {
#pragma unroll
    for (int r = 0; r < 4; ++r) {
      int row = rbase + nt * 16 + g * 4 + r;
      float q0 = acc[nt][0][r] + qb0, q1 = acc[nt][1][r] + qb1;
      float ssq = q0 * q0 + q1 * q1;
      ssq += __shfl_xor(ssq, 1); ssq += __shfl_xor(ssq, 2);
      ssq += __shfl_xor(ssq, 4); ssq += __shfl_xor(ssq, 8);
      float siq = sch / sqrtf(ssq);
      qn[row * 40 + c] = f2bf(q0 * siq);
      qn[row * 40 + 16 + c] = f2bf(q1 * siq);
      float k0v = acc[nt][2][r] + kb0, k1v = acc[nt][3][r] + kb1;
      float ssk = k0v * k0v + k1v * k1v;
      ssk += __shfl_xor(ssk, 1); ssk += __shfl_xor(ssk, 2);
      ssk += __shfl_xor(ssk, 4); ssk += __shfl_xor(ssk, 8);
      float sik = 1.f / sqrtf(ssk);
      kn[row * 40 + c] = f2bf(k0v * sik);
      kn[row * 40 + 16 + c] = f2bf(k1v * sik);
      float v0 = acc[nt][4][r] + vb0;
      float v1 = acc[nt][5][r] + vb1;
      vT[c * 168 + row] = f2bf(v0);
      vT[(16 + c) * 168 + row] = f2bf(v1);
    }
  }
  if (tid < 32) {  // zero the m-pad (144..167) so padded-K MFMA adds 0
    uint4 z4 = {0u, 0u, 0u, 0u};
    *(uint4*)(vT + tid * 168 + 144) = z4;
    *(uint4*)(vT + tid * 168 + 152) = z4;
    *(uint4*)(vT + tid * 168 + 160) = z4;
  }
  __syncthreads();

  // ---- phase 3: S = qn . kn^T (16x16x32 MFMA, K=d=32) ----
  short8 aq[3];
#pragma unroll
  for (int nt = 0; nt < 3; ++nt)
    aq[nt] = *(const short8*)(qn + (rbase + nt * 16 + c) * 40 + g * 8);
  f32x4 S[3][9];
#pragma unroll
  for (int mt = 0; mt < 9; ++mt) {
    short8 bk = *(const short8*)(kn + (mt * 16 + c) * 40 + g * 8);
#pragma unroll
    for (int nt = 0; nt < 3; ++nt) {
      f32x4 z = (f32x4){0.f, 0.f, 0.f, 0.f};
      S[nt][mt] = MFMA(aq[nt], bk, z);
    }
  }

  // ---- phase 4: + (rpb + mask), row softmax (folded 1/sum into P) ----
  const float* cbh = cb + (((size_t)w * NHEADS + h) * NTOK) * NTOK;
#pragma unroll
  for (int nt = 0; nt < 3; ++nt) {
#pragma unroll
    for (int r = 0; r < 4; ++r) {
      int row = rbase + nt * 16 + g * 4 + r;
      const float* crow = cbh + (size_t)row * NTOK + c;
      float sv[9];
      float mx = -1e30f;
#pragma unroll
      for (int mt = 0; mt < 9; ++mt) {
        float s = S[nt][mt][r] + crow[mt * 16];
        sv[mt] = s;
        mx = fmaxf(mx, s);
      }
      mx = fmaxf(mx, __shfl_xor(mx, 1)); mx = fmaxf(mx, __shfl_xor(mx, 2));
      mx = fmaxf(mx, __shfl_xor(mx, 4)); mx = fmaxf(mx, __shfl_xor(mx, 8));
      float sum = 0.f;
#pragma unroll
      for (int mt = 0; mt < 9; ++mt) {
        float p = __expf(sv[mt] - mx);
        sv[mt] = p;
        sum += p;
      }
      sum += __shfl_xor(sum, 1); sum += __shfl_xor(sum, 2);
      sum += __shfl_xor(sum, 4); sum += __shfl_xor(sum, 8);
      float rinv = 1.f / sum;
#pragma unroll
      for (int mt = 0; mt < 9; ++mt) S[nt][mt][r] = sv[mt] * rinv;
    }
  }

  // ---- phase 5: PV, K(m) chunked by 32 via per-wave P bounce in LDS ----
  f32x4 po[3][2];
#pragma unroll
  for (int a = 0; a < 3; ++a)
#pragma unroll
    for (int d = 0; d < 2; ++d) po[a][d] = (f32x4){0.f, 0.f, 0.f, 0.f};
  for (int ck = 0; ck < 5; ++ck) {
#pragma unroll
    for (int nt = 0; nt < 3; ++nt)
#pragma unroll
      for (int mt2 = 0; mt2 < 2; ++mt2) {
        int MT = ck * 2 + mt2;
#pragma unroll
        for (int r = 0; r < 4; ++r) {
          int row = rbase + nt * 16 + g * 4 + r;
          float p = (MT < 9) ? S[nt][MT][r] : 0.f;
          Pc[row * 40 + mt2 * 16 + c] = f2bf(p);
        }
      }
#pragma unroll
    for (int nt = 0; nt < 3; ++nt) {
      short8 pa = *(const short8*)(Pc + (rbase + nt * 16 + c) * 40 + g * 8);
#pragma unroll
      for (int dt = 0; dt < 2; ++dt) {
        short8 vb = *(const short8*)(vT + (dt * 16 + c) * 168 + ck * 32 + g * 8);
        po[nt][dt] = MFMA(pa, vb, po[nt][dt]);
      }
    }
  }

  // ---- epilogue: ctx[b*144+n][h*32+d] bf16 ----
#pragma unroll
  for (int nt = 0; nt < 3; ++nt)
#pragma unroll
    for (int dt = 0; dt < 2; ++dt)
#pragma unroll
      for (int r = 0; r < 4; ++r) {
        int n = rbase + nt * 16 + g * 4 + r;
        ctx[((size_t)b * NTOK + n) * DIMC + h * 32 + dt * 16 + c] = f2bf(po[nt][dt][r]);
      }
}

// ---------------- output projection: (73728 x 384) @ (384 x 384)^T + bias, bf16 MFMA ----------------
__global__ __launch_bounds__(256) void proj_gemm(const u16* __restrict__ ctx,
                                                 const u16* __restrict__ pwb,
                                                 const float* __restrict__ proj_b,
                                                 float* __restrict__ out) {
  __shared__ u16 As[128 * 64];
  __shared__ u16 Bs[128 * 64];
  int bid = blockIdx.x;
  int nblk = bid % 3, mblk = bid / 3;
  size_t gm0 = (size_t)mblk * 128;
  int gn0 = nblk * 128;
  int tid = threadIdx.x, lane = tid & 63, wid = tid >> 6;
  int wr = wid >> 1, wc = wid & 1, g = lane >> 4, c = lane & 15;
  f32x4 acc[4][4];
#pragma unroll
  for (int i = 0; i < 4; ++i)
#pragma unroll
    for (int j = 0; j < 4; ++j) acc[i][j] = (f32x4){0.f, 0.f, 0.f, 0.f};

  for (int t = 0; t < 6; ++t) {
    int k0 = t * 64;
#pragma unroll
    for (int p = 0; p < 4; ++p) {
      int row = p * 32 + (tid >> 3);
      int seg = (tid & 7) * 8;
      uint4 va = *(const uint4*)(ctx + (gm0 + row) * DIMC + k0 + seg);
      *(uint4*)(As + row * 64 + seg) = va;
      uint4 vb = *(const uint4*)(pwb + (size_t)(gn0 + row) * DIMC + k0 + seg);
      *(uint4*)(Bs + row * 64 + seg) = vb;
    }
    __syncthreads();
#pragma unroll
    for (int kk = 0; kk < 64; kk += 32) {
      short8 a[4], bfr[4];
#pragma unroll
      for (int mi = 0; mi < 4; ++mi)
        a[mi] = *(const short8*)(As + (wr * 64 + mi * 16 + c) * 64 + kk + g * 8);
#pragma unroll
      for (int ni = 0; ni < 4; ++ni)
        bfr[ni] = *(const short8*)(Bs + (wc * 64 + ni * 16 + c) * 64 + kk + g * 8);
#pragma unroll
      for (int mi = 0; mi < 4; ++mi)
#pragma unroll
        for (int ni = 0; ni < 4; ++ni)
          acc[mi][ni] = MFMA(a[mi], bfr[ni], acc[mi][ni]);
    }
    __syncthreads();
  }
#pragma unroll
  for (int mi = 0; mi < 4; ++mi)
#pragma unroll
    for (int ni = 0; ni < 4; ++ni) {
      int gcol = gn0 + wc * 64 + ni * 16 + c;
      float bv = proj_b[gcol];
#pragma unroll
      for (int r = 0; r < 4; ++r) {
        size_t grow = gm0 + wr * 64 + mi * 16 + g * 4 + r;
        out[grow * DIMC + gcol] = acc[mi][ni][r] + bv;
      }
    }
}

extern "C" void kernel_launch(void* const* d_in, const int* in_sizes, int n_in,
                              void* d_out, int out_size, void* d_ws, size_t ws_size,
                              hipStream_t stream) {
  const float* x = (const float*)d_in[0];
  const float* rct = (const float*)d_in[1];
  const int* rpi = (const int*)d_in[2];
  const float* mask = (const float*)d_in[3];
  const float* qkv_w = (const float*)d_in[4];
  const float* q_bias = (const float*)d_in[5];
  const float* k_bias = (const float*)d_in[6];
  const float* v_bias = (const float*)d_in[7];
  const float* logit_scale = (const float*)d_in[8];
  const float* cpb_w1 = (const float*)d_in[9];
  const float* cpb_b1 = (const float*)d_in[10];
  const float* cpb_w2 = (const float*)d_in[11];
  const float* proj_w = (const float*)d_in[12];
  const float* proj_b = (const float*)d_in[13];
  float* out = (float*)d_out;

  char* ws = (char*)d_ws;
  size_t off = 0;
  auto alloc = [&](size_t bytes) {
    void* p = ws + off;
    off = (off + bytes + 255) & ~(size_t)255;
    return p;
  };
  const size_t NX = (size_t)BWIN * NTOK * DIMC;  // 28311552
  u16* xb = (u16*)alloc(NX * 2);
  u16* wqb = (u16*)alloc((size_t)3 * DIMC * DIMC * 2);
  u16* pwb = (u16*)alloc((size_t)DIMC * DIMC * 2);
  u16* ctx = (u16*)alloc(NX * 2);
  float* cbv = (float*)alloc((size_t)NWIN * NHEADS * NTOK * NTOK * 4);
  float* bias_tab = (float*)alloc((size_t)TABLEN * NHEADS * 4);
  float* scalev = (float*)alloc(64 * 4);

  cvt_bf16<<<(int)(NX / 8 + 255) / 256, 256, 0, stream>>>(x, xb, (int)(NX / 8));
  cvt_bf16<<<(3 * DIMC * DIMC / 8 + 255) / 256, 256, 0, stream>>>(qkv_w, wqb, 3 * DIMC * DIMC / 8);
  cvt_bf16<<<(DIMC * DIMC / 8 + 255) / 256, 256, 0, stream>>>(proj_w, pwb, DIMC * DIMC / 8);
  cpb_kernel<<<(TABLEN * NHEADS + 255) / 256, 256, 0, stream>>>(
      rct, cpb_w1, cpb_b1, cpb_w2, logit_scale, bias_tab, scalev);
  cbias_kernel<<<(NWIN * NHEADS * NTOK * NTOK + 255) / 256, 256, 0, stream>>>(
      rpi, bias_tab, mask, cbv);
  attn_fused<<<BWIN * NHEADS, 192, 0, stream>>>(
      xb, wqb, q_bias, k_bias, v_bias, cbv, scalev, ctx);
  proj_gemm<<<(BWIN * NTOK / 128) * 3, 256, 0, stream>>>(ctx, pwb, proj_b, out);
}

// Round 10
// 508.857 us; speedup vs baseline: 1.0017x; 1.0017x over previous
//
#include <hip/hip_runtime.h>

#define DIMC 384
#define NHEADS 12
#define NTOK 144
#define TABLEN 529
#define BWIN 512
#define NWIN 16
#define CPBH 512

typedef unsigned short u16;
typedef unsigned int u32;
typedef __attribute__((ext_vector_type(8))) short short8;
typedef __attribute__((ext_vector_type(4))) float f32x4;

#define MFMA(a, b, c) __builtin_amdgcn_mfma_f32_16x16x32_bf16((a), (b), (c), 0, 0, 0)

__device__ __forceinline__ u16 f2bf(float f) {
  union { float f; u32 u; } v; v.f = f;
  u32 r = v.u + 0x7fffu + ((v.u >> 16) & 1u);
  return (u16)(r >> 16);
}
__device__ __forceinline__ u32 pk2(float a, float b) {
  return (u32)f2bf(a) | ((u32)f2bf(b) << 16);
}
__device__ __forceinline__ int swz4(int r) { return (r ^ (r >> 2)) & 3; }

// ---------------- f32 -> bf16 bulk convert ----------------
__global__ __launch_bounds__(256) void cvt_bf16(const float* __restrict__ in,
                                                u16* __restrict__ out, int n8) {
  int i = blockIdx.x * 256 + threadIdx.x;
  if (i >= n8) return;
  const float4* p = (const float4*)(in + (size_t)i * 8);
  float4 a = p[0], b = p[1];
  uint4 r;
  r.x = pk2(a.x, a.y); r.y = pk2(a.z, a.w);
  r.z = pk2(b.x, b.y); r.w = pk2(b.z, b.w);
  *(uint4*)(out + (size_t)i * 8) = r;
}

// ---------------- CPB-MLP table (529 x 12, sigmoid applied) + per-head scales ----------------
__global__ void cpb_kernel(const float* __restrict__ rct,
                           const float* __restrict__ w1,
                           const float* __restrict__ b1,
                           const float* __restrict__ w2,
                           const float* __restrict__ logit_scale,
                           float* __restrict__ bias_tab,
                           float* __restrict__ scalev) {
  int t = blockIdx.x * blockDim.x + threadIdx.x;
  if (t < NHEADS) scalev[t] = __expf(fminf(logit_scale[t], 4.60517018598809f));
  if (t >= TABLEN * NHEADS) return;
  int i = t / NHEADS, h = t % NHEADS;
  float c0 = rct[2 * i], c1 = rct[2 * i + 1];
  const float* w2h = w2 + (size_t)h * CPBH;
  float acc = 0.f;
  for (int k = 0; k < CPBH; ++k) {
    float hv = fmaxf(0.f, fmaf(c0, w1[2 * k], fmaf(c1, w1[2 * k + 1], b1[k])));
    acc = fmaf(hv, w2h[k], acc);
  }
  bias_tab[i * NHEADS + h] = 16.f / (1.f + __expf(-acc));
}

// ---------------- combined bias: cb[w][h][n][m] = rpb + mask (fp32) ----------------
__global__ __launch_bounds__(256) void cbias_kernel(const int* __restrict__ rpi,
                                                    const float* __restrict__ bias_tab,
                                                    const float* __restrict__ mask,
                                                    float* __restrict__ cb) {
  int e = blockIdx.x * 256 + threadIdx.x;
  if (e >= NWIN * NHEADS * NTOK * NTOK) return;
  int m = e % NTOK;
  int t = e / NTOK;
  int n = t % NTOK; t /= NTOK;
  int h = t % NHEADS;
  int w = t / NHEADS;
  cb[e] = bias_tab[rpi[n * NTOK + m] * NHEADS + h] + mask[(w * NTOK + n) * NTOK + m];
}

// ---------------- fused QKV-projection + cosine attention per (window b, head h) ----------------
// 192 threads = 3 waves; wave wv owns query rows [48wv, 48wv+48).
// Block decode is w-grouped per XCD: XCD x handles mask-windows {2x, 2x+1} so its
// cb working set (2 x 1.2MB) fits the 4MB XCD L2. Heads of one b are consecutive bids.
// Phase 1 = R2-proven register-prefetch schedule (K=32, loads issued one full iter
// ahead; 124 VGPR, zero spill) with R6-proven XOR-swizzled staging (conflict-free).
__global__ __launch_bounds__(192) void attn_fused(
    const u16* __restrict__ xb, const u16* __restrict__ wb,
    const float* __restrict__ q_bias, const float* __restrict__ k_bias,
    const float* __restrict__ v_bias, const float* __restrict__ cb,
    const float* __restrict__ scalev, u16* __restrict__ ctx) {
  __shared__ u16 smem[22656];  // 45312 B -> 3 blocks/CU
  u16* qn = smem;               // [144][40] (phase 2+)
  u16* kn = smem + 5760;        // [144][40] (phase 2+)
  u16* vT = smem + 11520;       // [32][168] (phase 2+)
  u16* Pc = smem + 16896;       // [144][40] (phase 5)
  u16* xs = smem;               // phase 1: [144][32] swizzled x chunk (9216 B)
  u16* wsm = smem + 4608;       // phase 1: [96][32] swizzled W chunk (6144 B)

  // w-grouped XCD decode
  int bid = blockIdx.x;
  int xcd = bid & 7;
  int i = bid >> 3;          // 0..767
  int wsub = i / 384;        // 0..1
  int j = i - wsub * 384;    // 0..383
  int bI = j / NHEADS;       // 0..31
  int h = j - bI * NHEADS;   // 0..11
  int w = xcd * 2 + wsub;    // 0..15
  int b = bI * NWIN + w;     // 0..511

  int tid = threadIdx.x;
  int lane = tid & 63, wv = tid >> 6;
  int g = lane >> 4, c = lane & 15;
  int rbase = wv * 48;

  // ---- phase 1: QKV projection via MFMA, K chunked by 32 (R2 schedule) ----
  f32x4 acc[3][6];
#pragma unroll
  for (int a = 0; a < 3; ++a)
#pragma unroll
    for (int d = 0; d < 6; ++d) acc[a][d] = (f32x4){0.f, 0.f, 0.f, 0.f};

  int r4 = tid >> 2, b4 = tid & 3;
  uint4 px[3], pw[2];
#pragma unroll
  for (int p = 0; p < 3; ++p)
    px[p] = *(const uint4*)(xb + ((size_t)b * NTOK + p * 48 + r4) * DIMC + b4 * 8);
#pragma unroll
  for (int p = 0; p < 2; ++p) {
    int row = p * 48 + r4;
    int wrow = (row >> 5) * DIMC + h * 32 + (row & 31);
    pw[p] = *(const uint4*)(wb + (size_t)wrow * DIMC + b4 * 8);
  }

  for (int t = 0; t < 12; ++t) {
    // swizzled staging writes (content block b4 -> slot b4 ^ swz4(row))
#pragma unroll
    for (int p = 0; p < 3; ++p) {
      int row = p * 48 + r4;
      *(uint4*)(xs + row * 32 + 8 * (b4 ^ swz4(row))) = px[p];
    }
#pragma unroll
    for (int p = 0; p < 2; ++p) {
      int row = p * 48 + r4;
      *(uint4*)(wsm + row * 32 + 8 * (b4 ^ swz4(row))) = pw[p];
    }
    __syncthreads();
    if (t < 11) {  // prefetch next tile into registers (one full iter of coverage)
      int k0 = (t + 1) * 32;
#pragma unroll
      for (int p = 0; p < 3; ++p)
        px[p] = *(const uint4*)(xb + ((size_t)b * NTOK + p * 48 + r4) * DIMC + k0 + b4 * 8);
#pragma unroll
      for (int p = 0; p < 2; ++p) {
        int row = p * 48 + r4;
        int wrow = (row >> 5) * DIMC + h * 32 + (row & 31);
        pw[p] = *(const uint4*)(wb + (size_t)wrow * DIMC + k0 + b4 * 8);
      }
    }
    short8 ax[3];
#pragma unroll
    for (int nt = 0; nt < 3; ++nt) {
      int row = rbase + nt * 16 + c;
      ax[nt] = *(const short8*)(xs + row * 32 + 8 * (g ^ swz4(row)));
    }
#pragma unroll
    for (int ni = 0; ni < 6; ++ni) {
      int row = ni * 16 + c;
      short8 bw = *(const short8*)(wsm + row * 32 + 8 * (g ^ swz4(row)));
#pragma unroll
      for (int nt = 0; nt < 3; ++nt) acc[nt][ni] = MFMA(ax[nt], bw, acc[nt][ni]);
    }
    __syncthreads();
  }

  // ---- phase 2: bias + cosine-normalize in-register, write qn/kn/vT (R2-proven) ----
  float sch = scalev[h];
  float qb0 = q_bias[h * 32 + c], qb1 = q_bias[h * 32 + 16 + c];
  float kb0 = k_bias[h * 32 + c], kb1 = k_bias[h * 32 + 16 + c];
  float vb0 = v_bias[h * 32 + c], vb1 = v_bias[h * 32 + 16 + c];
#pragma unroll
  for (int nt = 0; nt < 3; ++nt) {
#pragma unroll
    for (int r = 0; r < 4; ++r) {
      int row = rbase + nt * 16 + g * 4 + r;
      float q0 = acc[nt][0][r] + qb0, q1 = acc[nt][1][r] + qb1;
      float ssq = q0 * q0 + q1 * q1;
      ssq += __shfl_xor(ssq, 1); ssq += __shfl_xor(ssq, 2);
      ssq += __shfl_xor(ssq, 4); ssq += __shfl_xor(ssq, 8);
      float siq = sch / sqrtf(ssq);
      qn[row * 40 + c] = f2bf(q0 * siq);
      qn[row * 40 + 16 + c] = f2bf(q1 * siq);
      float k0v = acc[nt][2][r] + kb0, k1v = acc[nt][3][r] + kb1;
      float ssk = k0v * k0v + k1v * k1v;
      ssk += __shfl_xor(ssk, 1); ssk += __shfl_xor(ssk, 2);
      ssk += __shfl_xor(ssk, 4); ssk += __shfl_xor(ssk, 8);
      float sik = 1.f / sqrtf(ssk);
      kn[row * 40 + c] = f2bf(k0v * sik);
      kn[row * 40 + 16 + c] = f2bf(k1v * sik);
      float v0 = acc[nt][4][r] + vb0;
      float v1 = acc[nt][5][r] + vb1;
      vT[c * 168 + row] = f2bf(v0);
      vT[(16 + c) * 168 + row] = f2bf(v1);
    }
  }
  if (tid < 32) {  // zero the m-pad (144..167) so padded-K MFMA adds 0
    uint4 z4 = {0u, 0u, 0u, 0u};
    *(uint4*)(vT + tid * 168 + 144) = z4;
    *(uint4*)(vT + tid * 168 + 152) = z4;
    *(uint4*)(vT + tid * 168 + 160) = z4;
  }
  __syncthreads();

  // ---- phase 3: S = qn . kn^T (16x16x32 MFMA, K=d=32) ----
  short8 aq[3];
#pragma unroll
  for (int nt = 0; nt < 3; ++nt)
    aq[nt] = *(const short8*)(qn + (rbase + nt * 16 + c) * 40 + g * 8);
  f32x4 S[3][9];
#pragma unroll
  for (int mt = 0; mt < 9; ++mt) {
    short8 bk = *(const short8*)(kn + (mt * 16 + c) * 40 + g * 8);
#pragma unroll
    for (int nt = 0; nt < 3; ++nt) {
      f32x4 z = (f32x4){0.f, 0.f, 0.f, 0.f};
      S[nt][mt] = MFMA(aq[nt], bk, z);
    }
  }

  // ---- phase 4: + (rpb + mask), row softmax (folded 1/sum into P) ----
  const float* cbh = cb + (((size_t)w * NHEADS + h) * NTOK) * NTOK;
#pragma unroll
  for (int nt = 0; nt < 3; ++nt) {
#pragma unroll
    for (int r = 0; r < 4; ++r) {
      int row = rbase + nt * 16 + g * 4 + r;
      const float* crow = cbh + (size_t)row * NTOK + c;
      float sv[9];
      float mx = -1e30f;
#pragma unroll
      for (int mt = 0; mt < 9; ++mt) {
        float s = S[nt][mt][r] + crow[mt * 16];
        sv[mt] = s;
        mx = fmaxf(mx, s);
      }
      mx = fmaxf(mx, __shfl_xor(mx, 1)); mx = fmaxf(mx, __shfl_xor(mx, 2));
      mx = fmaxf(mx, __shfl_xor(mx, 4)); mx = fmaxf(mx, __shfl_xor(mx, 8));
      float sum = 0.f;
#pragma unroll
      for (int mt = 0; mt < 9; ++mt) {
        float p = __expf(sv[mt] - mx);
        sv[mt] = p;
        sum += p;
      }
      sum += __shfl_xor(sum, 1); sum += __shfl_xor(sum, 2);
      sum += __shfl_xor(sum, 4); sum += __shfl_xor(sum, 8);
      float rinv = 1.f / sum;
#pragma unroll
      for (int mt = 0; mt < 9; ++mt) S[nt][mt][r] = sv[mt] * rinv;
    }
  }

  // ---- phase 5: PV, K(m) chunked by 32 via per-wave P bounce in LDS ----
  f32x4 po[3][2];
#pragma unroll
  for (int a = 0; a < 3; ++a)
#pragma unroll
    for (int d = 0; d < 2; ++d) po[a][d] = (f32x4){0.f, 0.f, 0.f, 0.f};
  for (int ck = 0; ck < 5; ++ck) {
#pragma unroll
    for (int nt = 0; nt < 3; ++nt)
#pragma unroll
      for (int mt2 = 0; mt2 < 2; ++mt2) {
        int MT = ck * 2 + mt2;
#pragma unroll
        for (int r = 0; r < 4; ++r) {
          int row = rbase + nt * 16 + g * 4 + r;
          float p = (MT < 9) ? S[nt][MT][r] : 0.f;
          Pc[row * 40 + mt2 * 16 + c] = f2bf(p);
        }
      }
#pragma unroll
    for (int nt = 0; nt < 3; ++nt) {
      short8 pa = *(const short8*)(Pc + (rbase + nt * 16 + c) * 40 + g * 8);
#pragma unroll
      for (int dt = 0; dt < 2; ++dt) {
        short8 vb = *(const short8*)(vT + (dt * 16 + c) * 168 + ck * 32 + g * 8);
        po[nt][dt] = MFMA(pa, vb, po[nt][dt]);
      }
    }
  }

  // ---- epilogue: ctx[b*144+n][h*32+d] bf16 ----
#pragma unroll
  for (int nt = 0; nt < 3; ++nt)
#pragma unroll
    for (int dt = 0; dt < 2; ++dt)
#pragma unroll
      for (int r = 0; r < 4; ++r) {
        int n = rbase + nt * 16 + g * 4 + r;
        ctx[((size_t)b * NTOK + n) * DIMC + h * 32 + dt * 16 + c] = f2bf(po[nt][dt][r]);
      }
}

// ---------------- output projection: (73728 x 384) @ (384 x 384)^T + bias, bf16 MFMA ----------------
__global__ __launch_bounds__(256) void proj_gemm(const u16* __restrict__ ctx,
                                                 const u16* __restrict__ pwb,
                                                 const float* __restrict__ proj_b,
                                                 float* __restrict__ out) {
  __shared__ u16 As[128 * 64];
  __shared__ u16 Bs[128 * 64];
  int bid = blockIdx.x;
  int nblk = bid % 3, mblk = bid / 3;
  size_t gm0 = (size_t)mblk * 128;
  int gn0 = nblk * 128;
  int tid = threadIdx.x, lane = tid & 63, wid = tid >> 6;
  int wr = wid >> 1, wc = wid & 1, g = lane >> 4, c = lane & 15;
  f32x4 acc[4][4];
#pragma unroll
  for (int i = 0; i < 4; ++i)
#pragma unroll
    for (int j = 0; j < 4; ++j) acc[i][j] = (f32x4){0.f, 0.f, 0.f, 0.f};

  for (int t = 0; t < 6; ++t) {
    int k0 = t * 64;
#pragma unroll
    for (int p = 0; p < 4; ++p) {
      int row = p * 32 + (tid >> 3);
      int seg = (tid & 7) * 8;
      uint4 va = *(const uint4*)(ctx + (gm0 + row) * DIMC + k0 + seg);
      *(uint4*)(As + row * 64 + seg) = va;
      uint4 vb = *(const uint4*)(pwb + (size_t)(gn0 + row) * DIMC + k0 + seg);
      *(uint4*)(Bs + row * 64 + seg) = vb;
    }
    __syncthreads();
#pragma unroll
    for (int kk = 0; kk < 64; kk += 32) {
      short8 a[4], bfr[4];
#pragma unroll
      for (int mi = 0; mi < 4; ++mi)
        a[mi] = *(const short8*)(As + (wr * 64 + mi * 16 + c) * 64 + kk + g * 8);
#pragma unroll
      for (int ni = 0; ni < 4; ++ni)
        bfr[ni] = *(const short8*)(Bs + (wc * 64 + ni * 16 + c) * 64 + kk + g * 8);
#pragma unroll
      for (int mi = 0; mi < 4; ++mi)
#pragma unroll
        for (int ni = 0; ni < 4; ++ni)
          acc[mi][ni] = MFMA(a[mi], bfr[ni], acc[mi][ni]);
    }
    __syncthreads();
  }
#pragma unroll
  for (int mi = 0; mi < 4; ++mi)
#pragma unroll
    for (int ni = 0; ni < 4; ++ni) {
      int gcol = gn0 + wc * 64 + ni * 16 + c;
      float bv = proj_b[gcol];
#pragma unroll
      for (int r = 0; r < 4; ++r) {
        size_t grow = gm0 + wr * 64 + mi * 16 + g * 4 + r;
        out[grow * DIMC + gcol] = acc[mi][ni][r] + bv;
      }
    }
}

extern "C" void kernel_launch(void* const* d_in, const int* in_sizes, int n_in,
                              void* d_out, int out_size, void* d_ws, size_t ws_size,
                              hipStream_t stream) {
  const float* x = (const float*)d_in[0];
  const float* rct = (const float*)d_in[1];
  const int* rpi = (const int*)d_in[2];
  const float* mask = (const float*)d_in[3];
  const float* qkv_w = (const float*)d_in[4];
  const float* q_bias = (const float*)d_in[5];
  const float* k_bias = (const float*)d_in[6];
  const float* v_bias = (const float*)d_in[7];
  const float* logit_scale = (const float*)d_in[8];
  const float* cpb_w1 = (const float*)d_in[9];
  const float* cpb_b1 = (const float*)d_in[10];
  const float* cpb_w2 = (const float*)d_in[11];
  const float* proj_w = (const float*)d_in[12];
  const float* proj_b = (const float*)d_in[13];
  float* out = (float*)d_out;

  char* ws = (char*)d_ws;
  size_t off = 0;
  auto alloc = [&](size_t bytes) {
    void* p = ws + off;
    off = (off + bytes + 255) & ~(size_t)255;
    return p;
  };
  const size_t NX = (size_t)BWIN * NTOK * DIMC;  // 28311552
  u16* xb = (u16*)alloc(NX * 2);
  u16* wqb = (u16*)alloc((size_t)3 * DIMC * DIMC * 2);
  u16* pwb = (u16*)alloc((size_t)DIMC * DIMC * 2);
  u16* ctx = (u16*)alloc(NX * 2);
  float* cbv = (float*)alloc((size_t)NWIN * NHEADS * NTOK * NTOK * 4);
  float* bias_tab = (float*)alloc((size_t)TABLEN * NHEADS * 4);
  float* scalev = (float*)alloc(64 * 4);

  cvt_bf16<<<(int)(NX / 8 + 255) / 256, 256, 0, stream>>>(x, xb, (int)(NX / 8));
  cvt_bf16<<<(3 * DIMC * DIMC / 8 + 255) / 256, 256, 0, stream>>>(qkv_w, wqb, 3 * DIMC * DIMC / 8);
  cvt_bf16<<<(DIMC * DIMC / 8 + 255) / 256, 256, 0, stream>>>(proj_w, pwb, DIMC * DIMC / 8);
  cpb_kernel<<<(TABLEN * NHEADS + 255) / 256, 256, 0, stream>>>(
      rct, cpb_w1, cpb_b1, cpb_w2, logit_scale, bias_tab, scalev);
  cbias_kernel<<<(NWIN * NHEADS * NTOK * NTOK + 255) / 256, 256, 0, stream>>>(
      rpi, bias_tab, mask, cbv);
  attn_fused<<<BWIN * NHEADS, 192, 0, stream>>>(
      xb, wqb, q_bias, k_bias, v_bias, cbv, scalev, ctx);
  proj_gemm<<<(BWIN * NTOK / 128) * 3, 256, 0, stream>>>(ctx, pwb, proj_b, out);
}

// Round 11
// 366.974 us; speedup vs baseline: 1.3891x; 1.3866x over previous
//
#include <hip/hip_runtime.h>

#define DIMC 384
#define NHEADS 12
#define NTOK 144
#define TABLEN 529
#define BWIN 512
#define NWIN 16
#define CPBH 512

typedef unsigned short u16;
typedef unsigned int u32;
typedef __attribute__((ext_vector_type(8))) short short8;
typedef __attribute__((ext_vector_type(4))) float f32x4;

#define MFMA(a, b, c) __builtin_amdgcn_mfma_f32_16x16x32_bf16((a), (b), (c), 0, 0, 0)

__device__ __forceinline__ u16 f2bf(float f) {
  union { float f; u32 u; } v; v.f = f;
  u32 r = v.u + 0x7fffu + ((v.u >> 16) & 1u);
  return (u16)(r >> 16);
}
__device__ __forceinline__ u32 pk2(float a, float b) {
  return (u32)f2bf(a) | ((u32)f2bf(b) << 16);
}
__device__ __forceinline__ int swz4(int r) { return (r ^ (r >> 2)) & 3; }

// ---------------- f32 -> bf16 bulk convert ----------------
__global__ __launch_bounds__(256) void cvt_bf16(const float* __restrict__ in,
                                                u16* __restrict__ out, int n8) {
  int i = blockIdx.x * 256 + threadIdx.x;
  if (i >= n8) return;
  const float4* p = (const float4*)(in + (size_t)i * 8);
  float4 a = p[0], b = p[1];
  uint4 r;
  r.x = pk2(a.x, a.y); r.y = pk2(a.z, a.w);
  r.z = pk2(b.x, b.y); r.w = pk2(b.z, b.w);
  *(uint4*)(out + (size_t)i * 8) = r;
}

// ---------------- CPB-MLP table (529 x 12, sigmoid applied) + per-head scales ----------------
__global__ void cpb_kernel(const float* __restrict__ rct,
                           const float* __restrict__ w1,
                           const float* __restrict__ b1,
                           const float* __restrict__ w2,
                           const float* __restrict__ logit_scale,
                           float* __restrict__ bias_tab,
                           float* __restrict__ scalev) {
  int t = blockIdx.x * blockDim.x + threadIdx.x;
  if (t < NHEADS) scalev[t] = __expf(fminf(logit_scale[t], 4.60517018598809f));
  if (t >= TABLEN * NHEADS) return;
  int i = t / NHEADS, h = t % NHEADS;
  float c0 = rct[2 * i], c1 = rct[2 * i + 1];
  const float* w2h = w2 + (size_t)h * CPBH;
  float acc = 0.f;
  for (int k = 0; k < CPBH; ++k) {
    float hv = fmaxf(0.f, fmaf(c0, w1[2 * k], fmaf(c1, w1[2 * k + 1], b1[k])));
    acc = fmaf(hv, w2h[k], acc);
  }
  bias_tab[i * NHEADS + h] = 16.f / (1.f + __expf(-acc));
}

// ---------------- combined bias: cb[w][h][n][m] = rpb + mask (fp32) ----------------
__global__ __launch_bounds__(256) void cbias_kernel(const int* __restrict__ rpi,
                                                    const float* __restrict__ bias_tab,
                                                    const float* __restrict__ mask,
                                                    float* __restrict__ cb) {
  int e = blockIdx.x * 256 + threadIdx.x;
  if (e >= NWIN * NHEADS * NTOK * NTOK) return;
  int m = e % NTOK;
  int t = e / NTOK;
  int n = t % NTOK; t /= NTOK;
  int h = t % NHEADS;
  int w = t / NHEADS;
  cb[e] = bias_tab[rpi[n * NTOK + m] * NHEADS + h] + mask[(w * NTOK + n) * NTOK + m];
}

// ---------------- fused QKV-projection + cosine attention per (window b, head h) ----------------
// 576 threads = 9 waves; wave wv owns query rows [16wv, 16wv+16).
// This decomposition exists to kill register pressure: per-thread live state is
// acc[6] (24 VGPR) in phase 1 and S[9] (36 VGPR) in phases 3-5 — the 3-wave
// version (acc 72 / S 108) spilled ~110MB/dispatch at the 128-VGPR cliff in
// every variant (R3-R10). w-grouped XCD decode (FETCH 330->56MB, R10-proven).
__global__ __launch_bounds__(576) void attn_fused(
    const u16* __restrict__ xb, const u16* __restrict__ wb,
    const float* __restrict__ q_bias, const float* __restrict__ k_bias,
    const float* __restrict__ v_bias, const float* __restrict__ cb,
    const float* __restrict__ scalev, u16* __restrict__ ctx) {
  __shared__ u16 smem[22656];  // 45312 B -> 3 blocks/CU (LDS-wise)
  u16* qn = smem;               // [144][40] (phase 2+)
  u16* kn = smem + 5760;        // [144][40] (phase 2+)
  u16* vT = smem + 11520;       // [32][168] (phase 2+)
  u16* Pc = smem + 16896;       // [144][40] (phase 5, wave-private 16-row slices)
  u16* xs = smem;               // phase 1: [144][32] swizzled x chunk (9216 B)
  u16* wsm = smem + 4608;       // phase 1: [96][32] swizzled W chunk (6144 B)

  // w-grouped XCD decode: XCD x owns mask-windows {2x,2x+1}; cb set = 2.4MB < 4MB L2
  int bid = blockIdx.x;
  int xcd = bid & 7;
  int i = bid >> 3;
  int wsub = i / 384;
  int j = i - wsub * 384;
  int bI = j / NHEADS;
  int h = j - bI * NHEADS;
  int w = xcd * 2 + wsub;
  int b = bI * NWIN + w;

  int tid = threadIdx.x;
  int lane = tid & 63, wv = tid >> 6;   // wv 0..8
  int g = lane >> 4, c = lane & 15;
  int rbase = wv * 16;

  // ---- phase 1: QKV projection via MFMA, K chunked by 32, reg-prefetch 1 iter ahead ----
  f32x4 acc[6];
#pragma unroll
  for (int d = 0; d < 6; ++d) acc[d] = (f32x4){0.f, 0.f, 0.f, 0.f};

  int r4 = tid >> 2, b4 = tid & 3;  // x chunk: row r4 (0..143), 16B-block b4
  bool hasW = tid < 384;            // W chunk: row r4 (0..95) on threads 0..383
  int wrow = (r4 >> 5) * DIMC + h * 32 + (r4 & 31);
  int xwo = r4 * 32 + 8 * (b4 ^ swz4(r4));  // swizzled LDS write offsets

  uint4 px, pw;
  px = *(const uint4*)(xb + ((size_t)b * NTOK + r4) * DIMC + b4 * 8);
  if (hasW) pw = *(const uint4*)(wb + (size_t)wrow * DIMC + b4 * 8);

  for (int t = 0; t < 12; ++t) {
    *(uint4*)(xs + xwo) = px;
    if (hasW) *(uint4*)(wsm + xwo) = pw;
    __syncthreads();
    if (t < 11) {  // prefetch next tile (full MFMA block of latency coverage)
      int k0 = (t + 1) * 32;
      px = *(const uint4*)(xb + ((size_t)b * NTOK + r4) * DIMC + k0 + b4 * 8);
      if (hasW) pw = *(const uint4*)(wb + (size_t)wrow * DIMC + k0 + b4 * 8);
    }
    int arow = rbase + c;
    short8 ax = *(const short8*)(xs + arow * 32 + 8 * (g ^ swz4(arow)));
#pragma unroll
    for (int ni = 0; ni < 6; ++ni) {
      int row = ni * 16 + c;
      short8 bw = *(const short8*)(wsm + row * 32 + 8 * (g ^ swz4(row)));
      acc[ni] = MFMA(ax, bw, acc[ni]);
    }
    __syncthreads();
  }

  // ---- phase 2: bias + cosine-normalize in-register, write qn/kn/vT ----
  float sch = scalev[h];
  float qb0 = q_bias[h * 32 + c], qb1 = q_bias[h * 32 + 16 + c];
  float kb0 = k_bias[h * 32 + c], kb1 = k_bias[h * 32 + 16 + c];
  float vb0 = v_bias[h * 32 + c], vb1 = v_bias[h * 32 + 16 + c];
#pragma unroll
  for (int r = 0; r < 4; ++r) {
    int row = rbase + g * 4 + r;
    float q0 = acc[0][r] + qb0, q1 = acc[1][r] + qb1;
    float ssq = q0 * q0 + q1 * q1;
    ssq += __shfl_xor(ssq, 1); ssq += __shfl_xor(ssq, 2);
    ssq += __shfl_xor(ssq, 4); ssq += __shfl_xor(ssq, 8);
    float siq = sch / sqrtf(ssq);
    qn[row * 40 + c] = f2bf(q0 * siq);
    qn[row * 40 + 16 + c] = f2bf(q1 * siq);
    float k0v = acc[2][r] + kb0, k1v = acc[3][r] + kb1;
    float ssk = k0v * k0v + k1v * k1v;
    ssk += __shfl_xor(ssk, 1); ssk += __shfl_xor(ssk, 2);
    ssk += __shfl_xor(ssk, 4); ssk += __shfl_xor(ssk, 8);
    float sik = 1.f / sqrtf(ssk);
    kn[row * 40 + c] = f2bf(k0v * sik);
    kn[row * 40 + 16 + c] = f2bf(k1v * sik);
    float v0 = acc[4][r] + vb0;
    float v1 = acc[5][r] + vb1;
    vT[c * 168 + row] = f2bf(v0);
    vT[(16 + c) * 168 + row] = f2bf(v1);
  }
  if (tid < 32) {  // zero the m-pad (144..167) so padded-K MFMA adds 0
    uint4 z4 = {0u, 0u, 0u, 0u};
    *(uint4*)(vT + tid * 168 + 144) = z4;
    *(uint4*)(vT + tid * 168 + 152) = z4;
    *(uint4*)(vT + tid * 168 + 160) = z4;
  }
  __syncthreads();

  // ---- phase 3: S = qn . kn^T (16x16x32 MFMA, K=d=32) ----
  short8 aq = *(const short8*)(qn + (rbase + c) * 40 + g * 8);
  f32x4 S[9];
#pragma unroll
  for (int mt = 0; mt < 9; ++mt) {
    short8 bk = *(const short8*)(kn + (mt * 16 + c) * 40 + g * 8);
    f32x4 z = (f32x4){0.f, 0.f, 0.f, 0.f};
    S[mt] = MFMA(aq, bk, z);
  }

  // ---- phase 4: + (rpb + mask), row softmax (folded 1/sum into P) ----
  const float* cbh = cb + (((size_t)w * NHEADS + h) * NTOK) * NTOK;
#pragma unroll
  for (int r = 0; r < 4; ++r) {
    int row = rbase + g * 4 + r;
    const float* crow = cbh + (size_t)row * NTOK + c;
    float sv[9];
    float mx = -1e30f;
#pragma unroll
    for (int mt = 0; mt < 9; ++mt) {
      float s = S[mt][r] + crow[mt * 16];
      sv[mt] = s;
      mx = fmaxf(mx, s);
    }
    mx = fmaxf(mx, __shfl_xor(mx, 1)); mx = fmaxf(mx, __shfl_xor(mx, 2));
    mx = fmaxf(mx, __shfl_xor(mx, 4)); mx = fmaxf(mx, __shfl_xor(mx, 8));
    float sum = 0.f;
#pragma unroll
    for (int mt = 0; mt < 9; ++mt) {
      float p = __expf(sv[mt] - mx);
      sv[mt] = p;
      sum += p;
    }
    sum += __shfl_xor(sum, 1); sum += __shfl_xor(sum, 2);
    sum += __shfl_xor(sum, 4); sum += __shfl_xor(sum, 8);
    float rinv = 1.f / sum;
#pragma unroll
    for (int mt = 0; mt < 9; ++mt) S[mt][r] = sv[mt] * rinv;
  }

  // ---- phase 5: PV, K(m) chunked by 32 via per-wave P bounce in LDS ----
  f32x4 po[2];
  po[0] = (f32x4){0.f, 0.f, 0.f, 0.f};
  po[1] = (f32x4){0.f, 0.f, 0.f, 0.f};
  for (int ck = 0; ck < 5; ++ck) {
#pragma unroll
    for (int mt2 = 0; mt2 < 2; ++mt2) {
      int MT = ck * 2 + mt2;
#pragma unroll
      for (int r = 0; r < 4; ++r) {
        int row = rbase + g * 4 + r;
        float p = (MT < 9) ? S[MT][r] : 0.f;
        Pc[row * 40 + mt2 * 16 + c] = f2bf(p);
      }
    }
    short8 pa = *(const short8*)(Pc + (rbase + c) * 40 + g * 8);
#pragma unroll
    for (int dt = 0; dt < 2; ++dt) {
      short8 vb = *(const short8*)(vT + (dt * 16 + c) * 168 + ck * 32 + g * 8);
      po[dt] = MFMA(pa, vb, po[dt]);
    }
  }

  // ---- epilogue: ctx[b*144+n][h*32+d] bf16 ----
#pragma unroll
  for (int dt = 0; dt < 2; ++dt)
#pragma unroll
    for (int r = 0; r < 4; ++r) {
      int n = rbase + g * 4 + r;
      ctx[((size_t)b * NTOK + n) * DIMC + h * 32 + dt * 16 + c] = f2bf(po[dt][r]);
    }
}

// ---------------- output projection: (73728 x 384) @ (384 x 384)^T + bias, bf16 MFMA ----------------
__global__ __launch_bounds__(256) void proj_gemm(const u16* __restrict__ ctx,
                                                 const u16* __restrict__ pwb,
                                                 const float* __restrict__ proj_b,
                                                 float* __restrict__ out) {
  __shared__ u16 As[128 * 64];
  __shared__ u16 Bs[128 * 64];
  int bid = blockIdx.x;
  int nblk = bid % 3, mblk = bid / 3;
  size_t gm0 = (size_t)mblk * 128;
  int gn0 = nblk * 128;
  int tid = threadIdx.x, lane = tid & 63, wid = tid >> 6;
  int wr = wid >> 1, wc = wid & 1, g = lane >> 4, c = lane & 15;
  f32x4 acc[4][4];
#pragma unroll
  for (int i = 0; i < 4; ++i)
#pragma unroll
    for (int j = 0; j < 4; ++j) acc[i][j] = (f32x4){0.f, 0.f, 0.f, 0.f};

  for (int t = 0; t < 6; ++t) {
    int k0 = t * 64;
#pragma unroll
    for (int p = 0; p < 4; ++p) {
      int row = p * 32 + (tid >> 3);
      int seg = (tid & 7) * 8;
      uint4 va = *(const uint4*)(ctx + (gm0 + row) * DIMC + k0 + seg);
      *(uint4*)(As + row * 64 + seg) = va;
      uint4 vb = *(const uint4*)(pwb + (size_t)(gn0 + row) * DIMC + k0 + seg);
      *(uint4*)(Bs + row * 64 + seg) = vb;
    }
    __syncthreads();
#pragma unroll
    for (int kk = 0; kk < 64; kk += 32) {
      short8 a[4], bfr[4];
#pragma unroll
      for (int mi = 0; mi < 4; ++mi)
        a[mi] = *(const short8*)(As + (wr * 64 + mi * 16 + c) * 64 + kk + g * 8);
#pragma unroll
      for (int ni = 0; ni < 4; ++ni)
        bfr[ni] = *(const short8*)(Bs + (wc * 64 + ni * 16 + c) * 64 + kk + g * 8);
#pragma unroll
      for (int mi = 0; mi < 4; ++mi)
#pragma unroll
        for (int ni = 0; ni < 4; ++ni)
          acc[mi][ni] = MFMA(a[mi], bfr[ni], acc[mi][ni]);
    }
    __syncthreads();
  }
#pragma unroll
  for (int mi = 0; mi < 4; ++mi)
#pragma unroll
    for (int ni = 0; ni < 4; ++ni) {
      int gcol = gn0 + wc * 64 + ni * 16 + c;
      float bv = proj_b[gcol];
#pragma unroll
      for (int r = 0; r < 4; ++r) {
        size_t grow = gm0 + wr * 64 + mi * 16 + g * 4 + r;
        out[grow * DIMC + gcol] = acc[mi][ni][r] + bv;
      }
    }
}

extern "C" void kernel_launch(void* const* d_in, const int* in_sizes, int n_in,
                              void* d_out, int out_size, void* d_ws, size_t ws_size,
                              hipStream_t stream) {
  const float* x = (const float*)d_in[0];
  const float* rct = (const float*)d_in[1];
  const int* rpi = (const int*)d_in[2];
  const float* mask = (const float*)d_in[3];
  const float* qkv_w = (const float*)d_in[4];
  const float* q_bias = (const float*)d_in[5];
  const float* k_bias = (const float*)d_in[6];
  const float* v_bias = (const float*)d_in[7];
  const float* logit_scale = (const float*)d_in[8];
  const float* cpb_w1 = (const float*)d_in[9];
  const float* cpb_b1 = (const float*)d_in[10];
  const float* cpb_w2 = (const float*)d_in[11];
  const float* proj_w = (const float*)d_in[12];
  const float* proj_b = (const float*)d_in[13];
  float* out = (float*)d_out;

  char* ws = (char*)d_ws;
  size_t off = 0;
  auto alloc = [&](size_t bytes) {
    void* p = ws + off;
    off = (off + bytes + 255) & ~(size_t)255;
    return p;
  };
  const size_t NX = (size_t)BWIN * NTOK * DIMC;  // 28311552
  u16* xb = (u16*)alloc(NX * 2);
  u16* wqb = (u16*)alloc((size_t)3 * DIMC * DIMC * 2);
  u16* pwb = (u16*)alloc((size_t)DIMC * DIMC * 2);
  u16* ctx = (u16*)alloc(NX * 2);
  float* cbv = (float*)alloc((size_t)NWIN * NHEADS * NTOK * NTOK * 4);
  float* bias_tab = (float*)alloc((size_t)TABLEN * NHEADS * 4);
  float* scalev = (float*)alloc(64 * 4);

  cvt_bf16<<<(int)(NX / 8 + 255) / 256, 256, 0, stream>>>(x, xb, (int)(NX / 8));
  cvt_bf16<<<(3 * DIMC * DIMC / 8 + 255) / 256, 256, 0, stream>>>(qkv_w, wqb, 3 * DIMC * DIMC / 8);
  cvt_bf16<<<(DIMC * DIMC / 8 + 255) / 256, 256, 0, stream>>>(proj_w, pwb, DIMC * DIMC / 8);
  cpb_kernel<<<(TABLEN * NHEADS + 255) / 256, 256, 0, stream>>>(
      rct, cpb_w1, cpb_b1, cpb_w2, logit_scale, bias_tab, scalev);
  cbias_kernel<<<(NWIN * NHEADS * NTOK * NTOK + 255) / 256, 256, 0, stream>>>(
      rpi, bias_tab, mask, cbv);
  attn_fused<<<BWIN * NHEADS, 576, 0, stream>>>(
      xb, wqb, q_bias, k_bias, v_bias, cbv, scalev, ctx);
  proj_gemm<<<(BWIN * NTOK / 128) * 3, 256, 0, stream>>>(ctx, pwb, proj_b, out);
}